// Round 9
// baseline (250.253 us; speedup 1.0000x reference)
//
#include <hip/hip_runtime.h>

// Problem constants
#define NHID 256
#define NV   21
#define NT   60
#define NC   4
#define NDCT 60
#define THIS 30
#define NBS  256

typedef float f32x2 __attribute__((ext_vector_type(2)));
typedef float f32x4 __attribute__((ext_vector_type(4)));

__device__ __forceinline__ float ftanh(float x) {
    // tanh(x) = 1 - 2/(exp(2x)+1); exact at +-inf, ~1e-6 rel error
    float e = __expf(2.0f * x);
    return 1.0f - __fdividef(2.0f, e + 1.0f);
}

// ---------------------------------------------------------------------------
// ONE kernel, one block per batch row n, 1024 threads (16 waves/CU).
// Phase 1 (STSGCN + encoders), phase 2 (residual MLP head + IDCT) in-block.
// Packed-fp32 (v_pk_fma_f32) math throughout the hot loops.
// ---------------------------------------------------------------------------
__global__ __launch_bounds__(1024, 4) void k_all(
    const float* __restrict__ x,
    const float* __restrict__ cont,
    const float* __restrict__ dct_m, const float* __restrict__ idct_m,
    const int* __restrict__ root_idx,
    const float* __restrict__ T_c, const float* __restrict__ A_c,
    const float* __restrict__ conv_w, const float* __restrict__ conv_b,
    const float* __restrict__ bn1_scale, const float* __restrict__ bn1_shift,
    const float* __restrict__ resconv_w, const float* __restrict__ resconv_b,
    const float* __restrict__ bnr_scale, const float* __restrict__ bnr_shift,
    const float* __restrict__ prelu_a_p,
    const float* __restrict__ te1_w, const float* __restrict__ te1_b,
    const float* __restrict__ te2_w, const float* __restrict__ te2_b,
    const float* __restrict__ ne1_w, const float* __restrict__ ne1_b,
    const float* __restrict__ ne2_w, const float* __restrict__ ne2_b,
    const float* __restrict__ g1_w, const float* __restrict__ g1_b,
    const float* __restrict__ g2a_w, const float* __restrict__ g2a_b,
    const float* __restrict__ g2b_w, const float* __restrict__ g2b_b,
    const float* __restrict__ g3a_w, const float* __restrict__ g3a_b,
    const float* __restrict__ g3b_w, const float* __restrict__ g3b_b,
    const float* __restrict__ g4_w, const float* __restrict__ g4_b,
    float* __restrict__ out)
{
    __shared__ __align__(16) float xc_lds[5040];   // [t][v][c]
    __shared__ __align__(16) float g_lds[5040];    // [q][v][c]; reused in phase 2
    __shared__ __align__(16) float g2_lds[5040];   // [t][w][c]

    // phase-2 scratch carved out of g_lds (dead after stage C):
    float* in2 = g_lds;          // [436] = concat(root_dct, hcont)
    float* aL  = g_lds + 436;    // [256]
    float* bL  = g_lds + 692;    // [256]
    float* rp  = g_lds + 948;    // [180]

    const int n   = blockIdx.x;
    const int tid = threadIdx.x;

    // ---- stage A: cont[n] -> LDS (layout already [t][v][c]) ----
    {
        const float4* src = (const float4*)(cont + n * 5040);
        float4* dst = (float4*)xc_lds;
        for (int i = tid; i < 1260; i += 1024) dst[i] = src[i];
    }
    __syncthreads();

    // ---- stage B: g[q][v][c] = sum_t xc[t][v][c] * T_c[v][t][q], q-pairs ----
    for (int task = tid; task < 630; task += 1024) {
        int v  = task / 30;           // 0..20
        int q0 = (task - v * 30) * 2; // 0,2,..,58
        const float* tc = T_c + v * 3600 + q0;   // + t*60
        f32x4 a0 = {0.f,0.f,0.f,0.f}, a1 = {0.f,0.f,0.f,0.f};
        #pragma unroll 4
        for (int t = 0; t < 60; ++t) {
            f32x4 xcv = *(const f32x4*)(xc_lds + t * 84 + v * 4);
            float2 tq = *(const float2*)(tc + t * 60);   // 8B-aligned (q0 even)
            a0 += xcv * tq.x;
            a1 += xcv * tq.y;
        }
        *(f32x4*)(g_lds + q0 * 84 + v * 4)       = a0;
        *(f32x4*)(g_lds + (q0 + 1) * 84 + v * 4) = a1;
    }
    __syncthreads();

    // ---- stage C: g2[t][w][c] = sum_v g[t][v][c] * A_c[t][v][w], w-pairs ----
    for (int task = tid; task < 660; task += 1024) {
        int t  = task / 11;            // 0..59
        int w0 = (task - t * 11) * 2;  // 0,2,..,20 (w0==20 -> single)
        const bool has2 = (w0 < 20);
        const float* ac = A_c + t * 441 + w0;   // + v*21
        f32x4 a0 = {0.f,0.f,0.f,0.f}, a1 = {0.f,0.f,0.f,0.f};
        #pragma unroll
        for (int v = 0; v < 21; ++v) {
            f32x4 gv = *(const f32x4*)(g_lds + t * 84 + v * 4);
            float b0 = ac[v * 21];
            float b1 = has2 ? ac[v * 21 + 1] : 0.f;
            a0 += gv * b0;
            a1 += gv * b1;
        }
        *(f32x4*)(g2_lds + t * 84 + w0 * 4) = a0;
        if (has2) *(f32x4*)(g2_lds + t * 84 + (w0 + 1) * 4) = a1;
    }
    __syncthreads();
    // g_lds is now dead as adjacency scratch -> becomes head scratch (in2/aL/bL/rp)

    // ---- root-history DCT for this row -> in2[0..179] (overlaps main loop) ----
    if (tid < 180) {
        int d = tid / 3, k = tid - d * 3;
        int ri = root_idx[k];
        const float* xp = x + n * 63 + ri;   // + t*16128
        const float* dm = dct_m + d * 90;
        float acc = 0.f;
        #pragma unroll
        for (int t = 0; t < 30; ++t)
            acc += dm[t] * xp[t * 16128];
        float wl = 0.f;
        #pragma unroll
        for (int t = 30; t < 90; ++t)
            wl += dm[t];
        acc += wl * xp[29 * 16128];
        in2[tid] = acc;
    }

    // ---- main fused loop: 2 o-channels per thread, packed-pair math ----
    {
        const int og = tid >> 3;     // 0..127 -> o = og*2+g
        const int part = tid & 7;    // 0..7   -> v slice
        const int vstart = (part < 5) ? part * 3 : 15 + (part - 5) * 2;
        const int vcount = (part < 5) ? 3 : 2;

        const float pa = prelu_a_p[0];

        f32x2 cA01[2], cA23[2], cB01[2], cB23[2];
        float cC[2];
        #pragma unroll
        for (int g = 0; g < 2; ++g) {
            int o = og * 2 + g;
            float s1 = bn1_scale[o], sr = bnr_scale[o];
            cA01[g] = (f32x2){conv_w[o*4+0] * s1, conv_w[o*4+1] * s1};
            cA23[g] = (f32x2){conv_w[o*4+2] * s1, conv_w[o*4+3] * s1};
            cB01[g] = (f32x2){resconv_w[o*4+0] * sr, resconv_w[o*4+1] * sr};
            cB23[g] = (f32x2){resconv_w[o*4+2] * sr, resconv_w[o*4+3] * sr};
            cC[g] = conv_b[o] * s1 + bn1_shift[o] + resconv_b[o] * sr + bnr_shift[o];
        }

        float tw2[10], tb1[10];
        #pragma unroll
        for (int j = 0; j < 10; ++j) { tw2[j] = te2_w[j]; tb1[j] = te1_b[j]; }
        const float tb2 = te2_b[0];

        float wacc[2][10];
        #pragma unroll
        for (int g = 0; g < 2; ++g)
            #pragma unroll
            for (int j = 0; j < 10; ++j) wacc[g][j] = 0.f;

        for (int vi = 0; vi < vcount; ++vi) {
            int v = vstart + vi;
            f32x2 u2[2][5];
            #pragma unroll
            for (int g = 0; g < 2; ++g)
                #pragma unroll
                for (int p = 0; p < 5; ++p)
                    u2[g][p] = (f32x2){tb1[2*p], tb1[2*p+1]};

            const float* xcp = xc_lds + v * 4;
            const float* g2p = g2_lds + v * 4;
            for (int t = 0; t < 60; ++t) {
                f32x4 xcv = *(const f32x4*)(xcp + t * 84);
                f32x4 g2v = *(const f32x4*)(g2p + t * 84);
                f32x2 g01 = {g2v.x, g2v.y}, g23 = {g2v.z, g2v.w};
                f32x2 x01 = {xcv.x, xcv.y}, x23 = {xcv.z, xcv.w};
                // tw: uniform address -> scalar loads
                const float* tewp = te1_w + t;
                f32x2 twp[5];
                #pragma unroll
                for (int p = 0; p < 5; ++p)
                    twp[p] = (f32x2){tewp[p * 120], tewp[p * 120 + 60]};
                #pragma unroll
                for (int g = 0; g < 2; ++g) {
                    f32x2 hv = {cC[g], 0.f};
                    hv += cA01[g] * g01;
                    hv += cA23[g] * g23;
                    hv += cB01[g] * x01;
                    hv += cB23[g] * x23;
                    float h = hv.x + hv.y;
                    h = fmaxf(h, 0.f) + pa * fminf(h, 0.f);   // PReLU
                    #pragma unroll
                    for (int p = 0; p < 5; ++p)
                        u2[g][p] += h * twp[p];
                }
            }

            float nw[10];
            #pragma unroll
            for (int j = 0; j < 10; ++j) nw[j] = ne1_w[j * 21 + v];
            #pragma unroll
            for (int g = 0; g < 2; ++g) {
                float s = tb2;
                #pragma unroll
                for (int p = 0; p < 5; ++p) {
                    s += ftanh(u2[g][p].x) * tw2[2*p];
                    s += ftanh(u2[g][p].y) * tw2[2*p+1];
                }
                s = ftanh(s);
                #pragma unroll
                for (int j = 0; j < 10; ++j) wacc[g][j] += s * nw[j];
            }
        }

        // butterfly reduce over the 8 v-parts (tid low 3 bits)
        #pragma unroll
        for (int d = 1; d < 8; d <<= 1)
            #pragma unroll
            for (int g = 0; g < 2; ++g)
                #pragma unroll
                for (int j = 0; j < 10; ++j)
                    wacc[g][j] += __shfl_xor(wacc[g][j], d, 64);

        if (part == 0) {
            float nw2[10];
            #pragma unroll
            for (int j = 0; j < 10; ++j) nw2[j] = ne2_w[j];
            float nb2 = ne2_b[0];
            #pragma unroll
            for (int g = 0; g < 2; ++g) {
                int o = og * 2 + g;
                float s = nb2;
                #pragma unroll
                for (int j = 0; j < 10; ++j)
                    s += ftanh(wacc[g][j] + ne1_b[j]) * nw2[j];
                in2[180 + o] = ftanh(s);     // hcont stays in LDS
            }
        }
    }
    __syncthreads();

    // ---- phase 2: residual MLP head, 4-lane k-split per output ----
    const int gid = tid >> 2;    // 0..255 = output index o
    const int sub = tid & 3;     // 0..3   = k-slice lane

// K inputs (NCHUNK float4 chunks), 256 outputs. BODY uses (o, sumv).
// Dual packed accumulators for ILP; lanes sub=0..3 cover chunk residues.
#define DENSE(KDIM, NCHUNK, W, SRC, BODY)                                      \
    {                                                                          \
        f32x4 accA = {0.f,0.f,0.f,0.f}, accB = {0.f,0.f,0.f,0.f};              \
        _Pragma("unroll")                                                      \
        for (int s = 0; s < (NCHUNK + 7) / 8; ++s) {                           \
            int c4 = s * 8 + sub;                                              \
            if (c4 < NCHUNK) {                                                 \
                f32x4 av = *(const f32x4*)&SRC[c4 * 4];                        \
                f32x4 wv = *(const f32x4*)&W[gid * KDIM + c4 * 4];             \
                accA += av * wv;                                               \
            }                                                                  \
            int c4b = s * 8 + 4 + sub;                                         \
            if (c4b < NCHUNK) {                                                \
                f32x4 av = *(const f32x4*)&SRC[c4b * 4];                       \
                f32x4 wv = *(const f32x4*)&W[gid * KDIM + c4b * 4];            \
                accB += av * wv;                                               \
            }                                                                  \
        }                                                                      \
        f32x4 accv = accA + accB;                                              \
        float acc = (accv.x + accv.y) + (accv.z + accv.w);                     \
        acc += __shfl_xor(acc, 1, 64);                                         \
        acc += __shfl_xor(acc, 2, 64);                                         \
        if (sub == 0) { int o = gid; float sumv = acc; BODY }                  \
    }                                                                          \
    __syncthreads();

    // g1: 436 -> 256, tanh
    DENSE(436, 109, g1_w, in2, { aL[o] = ftanh(sumv + g1_b[o]); })
    // g2a: 256 -> 256, tanh
    DENSE(256, 64, g2a_w, aL, { bL[o] = ftanh(sumv + g2a_b[o]); })
    // g2b: + residual
    DENSE(256, 64, g2b_w, bL, { aL[o] = ftanh(sumv + g2b_b[o]) + aL[o]; })
    // g3a
    DENSE(256, 64, g3a_w, aL, { bL[o] = ftanh(sumv + g3a_b[o]); })
    // g3b: + residual
    DENSE(256, 64, g3b_w, bL, { aL[o] = ftanh(sumv + g3b_b[o]) + aL[o]; })
    // g4: 256 -> 180, + root_his_dct residual
    DENSE(256, 64, g4_w, aL, { if (o < 180) rp[o] = sumv + g4_b[o] + in2[o]; })

    // ---- IDCT: out[n,t,k] = sum_d idct_m[t,d] * rp[d*3+k] ----
    if (tid < 270) {
        int t = tid / 3;
        int k = tid - t * 3;
        const float* im = idct_m + t * 60;
        const float* rpp = rp + k;
        float acc = 0.f;
        #pragma unroll
        for (int d = 0; d < 60; ++d)
            acc += im[d] * rpp[d * 3];
        out[n * 270 + tid] = acc;
    }
}

// ---------------------------------------------------------------------------
extern "C" void kernel_launch(void* const* d_in, const int* in_sizes, int n_in,
                              void* d_out, int out_size, void* d_ws, size_t ws_size,
                              hipStream_t stream)
{
    const float* x        = (const float*)d_in[0];
    const float* cont     = (const float*)d_in[1];
    // d_in[2] cont_mask unused
    const float* dct_m    = (const float*)d_in[3];
    const float* idct_m   = (const float*)d_in[4];
    const int*   root_idx = (const int*)d_in[5];
    // d_in[6] horizon unused (hardcoded 60)
    const float* T_c      = (const float*)d_in[7];
    const float* A_c      = (const float*)d_in[8];
    const float* conv_w   = (const float*)d_in[9];
    const float* conv_b   = (const float*)d_in[10];
    const float* bn1_s    = (const float*)d_in[11];
    const float* bn1_sh   = (const float*)d_in[12];
    const float* rconv_w  = (const float*)d_in[13];
    const float* rconv_b  = (const float*)d_in[14];
    const float* bnr_s    = (const float*)d_in[15];
    const float* bnr_sh   = (const float*)d_in[16];
    const float* prelu_a  = (const float*)d_in[17];
    const float* te1_w    = (const float*)d_in[18];
    const float* te1_b    = (const float*)d_in[19];
    const float* te2_w    = (const float*)d_in[20];
    const float* te2_b    = (const float*)d_in[21];
    const float* ne1_w    = (const float*)d_in[22];
    const float* ne1_b    = (const float*)d_in[23];
    const float* ne2_w    = (const float*)d_in[24];
    const float* ne2_b    = (const float*)d_in[25];
    const float* g1_w     = (const float*)d_in[26];
    const float* g1_b     = (const float*)d_in[27];
    const float* g2a_w    = (const float*)d_in[28];
    const float* g2a_b    = (const float*)d_in[29];
    const float* g2b_w    = (const float*)d_in[30];
    const float* g2b_b    = (const float*)d_in[31];
    const float* g3a_w    = (const float*)d_in[32];
    const float* g3a_b    = (const float*)d_in[33];
    const float* g3b_w    = (const float*)d_in[34];
    const float* g3b_b    = (const float*)d_in[35];
    const float* g4_w     = (const float*)d_in[36];
    const float* g4_b     = (const float*)d_in[37];

    k_all<<<NBS, 1024, 0, stream>>>(x, cont, dct_m, idct_m, root_idx,
                                    T_c, A_c,
                                    conv_w, conv_b, bn1_s, bn1_sh,
                                    rconv_w, rconv_b, bnr_s, bnr_sh,
                                    prelu_a,
                                    te1_w, te1_b, te2_w, te2_b,
                                    ne1_w, ne1_b, ne2_w, ne2_b,
                                    g1_w, g1_b, g2a_w, g2a_b, g2b_w, g2b_b,
                                    g3a_w, g3a_b, g3b_w, g3b_b, g4_w, g4_b,
                                    (float*)d_out);
}

// Round 11
// 249.458 us; speedup vs baseline: 1.0032x; 1.0032x over previous
//
#include <hip/hip_runtime.h>

// Problem constants
#define NHID 256
#define NV   21
#define NT   60
#define NC   4
#define NDCT 60
#define THIS 30
#define NBS  256
#define WSROW 448   // floats per row in ws hand-off buffer (16B-aligned)

typedef float f32x2 __attribute__((ext_vector_type(2)));
typedef float f32x4 __attribute__((ext_vector_type(4)));

__device__ __forceinline__ float ftanh(float x) {
    // tanh(x) = 1 - 2/(exp(2x)+1); exact at +-inf, ~1e-6 rel error
    float e = __expf(2.0f * x);
    return 1.0f - __fdividef(2.0f, e + 1.0f);
}

// ---------------------------------------------------------------------------
// Kernel 1: STSGCN + conv/BN/PReLU + time/node encoders + root-DCT.
// One block per batch row, 1024 threads. Writes concat(root_dct, hcont)
// into ws[n*WSROW + 0..435].
// tw (te1_w transposed) staged into LDS (g_lds scratch, dead after stage C)
// -> all main-loop lgkm ops are ORDERED ds_reads (no smem drain stalls).
// ---------------------------------------------------------------------------
__global__ __launch_bounds__(1024, 4) void k_p1(
    const float* __restrict__ x,
    const float* __restrict__ cont,
    const float* __restrict__ dct_m,
    const int* __restrict__ root_idx,
    const float* __restrict__ T_c, const float* __restrict__ A_c,
    const float* __restrict__ conv_w, const float* __restrict__ conv_b,
    const float* __restrict__ bn1_scale, const float* __restrict__ bn1_shift,
    const float* __restrict__ resconv_w, const float* __restrict__ resconv_b,
    const float* __restrict__ bnr_scale, const float* __restrict__ bnr_shift,
    const float* __restrict__ prelu_a_p,
    const float* __restrict__ te1_w, const float* __restrict__ te1_b,
    const float* __restrict__ te2_w, const float* __restrict__ te2_b,
    const float* __restrict__ ne1_w, const float* __restrict__ ne1_b,
    const float* __restrict__ ne2_w, const float* __restrict__ ne2_b,
    float* __restrict__ ws)
{
    __shared__ __align__(16) float xc_lds[5040];   // [t][v][c]
    __shared__ __align__(16) float g_lds[5040];    // [q][v][c]; then tew[60][10]
    __shared__ __align__(16) float g2_lds[5040];   // [t][w][c]

    const int n   = blockIdx.x;
    const int tid = threadIdx.x;

    // ---- stage A: cont[n] -> LDS (layout already [t][v][c]) ----
    {
        const float4* src = (const float4*)(cont + n * 5040);
        float4* dst = (float4*)xc_lds;
        for (int i = tid; i < 1260; i += 1024) dst[i] = src[i];
    }
    __syncthreads();

    // ---- stage B: g[q][v][c] = sum_t xc[t][v][c] * T_c[v][t][q], q-pairs ----
    for (int task = tid; task < 630; task += 1024) {
        int v  = task / 30;           // 0..20
        int q0 = (task - v * 30) * 2; // 0,2,..,58
        const float* tc = T_c + v * 3600 + q0;   // + t*60
        f32x4 a0 = {0.f,0.f,0.f,0.f}, a1 = {0.f,0.f,0.f,0.f};
        #pragma unroll 4
        for (int t = 0; t < 60; ++t) {
            f32x4 xcv = *(const f32x4*)(xc_lds + t * 84 + v * 4);
            float2 tq = *(const float2*)(tc + t * 60);   // 8B-aligned (q0 even)
            a0 += xcv * tq.x;
            a1 += xcv * tq.y;
        }
        *(f32x4*)(g_lds + q0 * 84 + v * 4)       = a0;
        *(f32x4*)(g_lds + (q0 + 1) * 84 + v * 4) = a1;
    }
    __syncthreads();

    // ---- stage C: g2[t][w][c] = sum_v g[t][v][c] * A_c[t][v][w], w-pairs ----
    for (int task = tid; task < 660; task += 1024) {
        int t  = task / 11;            // 0..59
        int w0 = (task - t * 11) * 2;  // 0,2,..,20 (w0==20 -> single)
        const bool has2 = (w0 < 20);
        const float* ac = A_c + t * 441 + w0;   // + v*21
        f32x4 a0 = {0.f,0.f,0.f,0.f}, a1 = {0.f,0.f,0.f,0.f};
        #pragma unroll
        for (int v = 0; v < 21; ++v) {
            f32x4 gv = *(const f32x4*)(g_lds + t * 84 + v * 4);
            float b0 = ac[v * 21];
            float b1 = has2 ? ac[v * 21 + 1] : 0.f;
            a0 += gv * b0;
            a1 += gv * b1;
        }
        *(f32x4*)(g2_lds + t * 84 + w0 * 4) = a0;
        if (has2) *(f32x4*)(g2_lds + t * 84 + (w0 + 1) * 4) = a1;
    }
    __syncthreads();
    // g_lds dead as adjacency scratch.

    float* tew = g_lds;   // [60][10] = te1_w transposed

    // ---- stage tew (te1_w [10][60] -> tew[t][j]) + root-DCT -> ws ----
    if (tid < 600) {
        int t = tid / 10, j = tid - t * 10;
        tew[t * 10 + j] = te1_w[j * 60 + t];
    } else if (tid >= 600 && tid < 780) {
        int r = tid - 600;
        int d = r / 3, k = r - d * 3;
        int ri = root_idx[k];
        const float* xp = x + n * 63 + ri;   // + t*16128
        const float* dm = dct_m + d * 90;
        float acc = 0.f;
        #pragma unroll
        for (int t = 0; t < 30; ++t)
            acc += dm[t] * xp[t * 16128];
        float wl = 0.f;
        #pragma unroll
        for (int t = 30; t < 90; ++t)
            wl += dm[t];
        acc += wl * xp[29 * 16128];
        ws[n * WSROW + r] = acc;
    }
    __syncthreads();

    // ---- main fused loop: 2 o-channels per thread ----
    {
        const int og = tid >> 3;     // 0..127 -> o = og*2+g
        const int part = tid & 7;    // 0..7   -> v slice
        const int vstart = (part < 5) ? part * 3 : 15 + (part - 5) * 2;
        const int vcount = (part < 5) ? 3 : 2;

        const float pa = prelu_a_p[0];

        f32x2 cA01[2], cA23[2], cB01[2], cB23[2];
        float cC[2];
        #pragma unroll
        for (int g = 0; g < 2; ++g) {
            int o = og * 2 + g;
            float s1 = bn1_scale[o], sr = bnr_scale[o];
            cA01[g] = (f32x2){conv_w[o*4+0] * s1, conv_w[o*4+1] * s1};
            cA23[g] = (f32x2){conv_w[o*4+2] * s1, conv_w[o*4+3] * s1};
            cB01[g] = (f32x2){resconv_w[o*4+0] * sr, resconv_w[o*4+1] * sr};
            cB23[g] = (f32x2){resconv_w[o*4+2] * sr, resconv_w[o*4+3] * sr};
            cC[g] = conv_b[o] * s1 + bn1_shift[o] + resconv_b[o] * sr + bnr_shift[o];
        }

        float tw2[10], tb1[10];
        #pragma unroll
        for (int j = 0; j < 10; ++j) { tw2[j] = te2_w[j]; tb1[j] = te1_b[j]; }
        const float tb2 = te2_b[0];

        float wacc[2][10];
        #pragma unroll
        for (int g = 0; g < 2; ++g)
            #pragma unroll
            for (int j = 0; j < 10; ++j) wacc[g][j] = 0.f;

        for (int vi = 0; vi < vcount; ++vi) {
            int v = vstart + vi;
            f32x2 u2[2][5];
            #pragma unroll
            for (int g = 0; g < 2; ++g)
                #pragma unroll
                for (int p = 0; p < 5; ++p)
                    u2[g][p] = (f32x2){tb1[2*p], tb1[2*p+1]};

            const float* xcp = xc_lds + v * 4;
            const float* g2p = g2_lds + v * 4;
            for (int t = 0; t < 60; ++t) {
                f32x4 xcv = *(const f32x4*)(xcp + t * 84);
                f32x4 g2v = *(const f32x4*)(g2p + t * 84);
                // tw: uniform-address LDS broadcasts (ordered lgkm, reg-packed)
                f32x2 tw[5];
                #pragma unroll
                for (int p = 0; p < 5; ++p)
                    tw[p] = *(const f32x2*)(tew + t * 10 + p * 2);
                f32x2 g01 = {g2v.x, g2v.y}, g23 = {g2v.z, g2v.w};
                f32x2 x01 = {xcv.x, xcv.y}, x23 = {xcv.z, xcv.w};
                #pragma unroll
                for (int g = 0; g < 2; ++g) {
                    f32x2 hv = {cC[g], 0.f};
                    hv += cA01[g] * g01;
                    hv += cA23[g] * g23;
                    hv += cB01[g] * x01;
                    hv += cB23[g] * x23;
                    float h = hv.x + hv.y;
                    h = fmaxf(h, 0.f) + pa * fminf(h, 0.f);   // PReLU
                    #pragma unroll
                    for (int p = 0; p < 5; ++p)
                        u2[g][p] += h * tw[p];
                }
            }

            float nw[10];
            #pragma unroll
            for (int j = 0; j < 10; ++j) nw[j] = ne1_w[j * 21 + v];
            #pragma unroll
            for (int g = 0; g < 2; ++g) {
                float s = tb2;
                #pragma unroll
                for (int p = 0; p < 5; ++p) {
                    s += ftanh(u2[g][p].x) * tw2[2*p];
                    s += ftanh(u2[g][p].y) * tw2[2*p+1];
                }
                s = ftanh(s);
                #pragma unroll
                for (int j = 0; j < 10; ++j) wacc[g][j] += s * nw[j];
            }
        }

        // butterfly reduce over the 8 v-parts (tid low 3 bits)
        #pragma unroll
        for (int d = 1; d < 8; d <<= 1)
            #pragma unroll
            for (int g = 0; g < 2; ++g)
                #pragma unroll
                for (int j = 0; j < 10; ++j)
                    wacc[g][j] += __shfl_xor(wacc[g][j], d, 64);

        if (part == 0) {
            float nw2[10];
            #pragma unroll
            for (int j = 0; j < 10; ++j) nw2[j] = ne2_w[j];
            float nb2 = ne2_b[0];
            #pragma unroll
            for (int g = 0; g < 2; ++g) {
                int o = og * 2 + g;
                float s = nb2;
                #pragma unroll
                for (int j = 0; j < 10; ++j)
                    s += ftanh(wacc[g][j] + ne1_b[j]) * nw2[j];
                ws[n * WSROW + 180 + o] = ftanh(s);
            }
        }
    }
}

// ---------------------------------------------------------------------------
// Kernel 2: residual MLP head + IDCT. One block per batch row, 1024 threads.
// 4-lane k-split per output (2 shfl rounds). Reads ws[n*WSROW + 0..435].
// ---------------------------------------------------------------------------
__global__ __launch_bounds__(1024, 4) void k_p2(
    const float* __restrict__ ws,
    const float* __restrict__ g1_w, const float* __restrict__ g1_b,
    const float* __restrict__ g2a_w, const float* __restrict__ g2a_b,
    const float* __restrict__ g2b_w, const float* __restrict__ g2b_b,
    const float* __restrict__ g3a_w, const float* __restrict__ g3a_b,
    const float* __restrict__ g3b_w, const float* __restrict__ g3b_b,
    const float* __restrict__ g4_w, const float* __restrict__ g4_b,
    const float* __restrict__ idct_m, float* __restrict__ out)
{
    __shared__ __align__(16) float in2[436];
    __shared__ __align__(16) float aL[256];
    __shared__ __align__(16) float bL[256];
    __shared__ __align__(16) float rp[180];

    const int n   = blockIdx.x;
    const int tid = threadIdx.x;

    // stage in2 from ws
    if (tid < 109) {
        *(f32x4*)(in2 + tid * 4) = *(const f32x4*)(ws + n * WSROW + tid * 4);
    }
    __syncthreads();

    const int gid = tid >> 2;    // 0..255 = output index o
    const int sub = tid & 3;     // 0..3   = k-slice lane

// K inputs (NCHUNK float4 chunks), 256 outputs. BODY uses (o, sumv).
#define DENSE(KDIM, NCHUNK, W, SRC, BODY)                                      \
    {                                                                          \
        f32x4 accA = {0.f,0.f,0.f,0.f}, accB = {0.f,0.f,0.f,0.f};              \
        _Pragma("unroll")                                                      \
        for (int s = 0; s < (NCHUNK + 7) / 8; ++s) {                           \
            int c4 = s * 8 + sub;                                              \
            if (c4 < NCHUNK) {                                                 \
                f32x4 av = *(const f32x4*)&SRC[c4 * 4];                        \
                f32x4 wv = *(const f32x4*)&W[gid * KDIM + c4 * 4];             \
                accA += av * wv;                                               \
            }                                                                  \
            int c4b = s * 8 + 4 + sub;                                         \
            if (c4b < NCHUNK) {                                                \
                f32x4 av = *(const f32x4*)&SRC[c4b * 4];                       \
                f32x4 wv = *(const f32x4*)&W[gid * KDIM + c4b * 4];            \
                accB += av * wv;                                               \
            }                                                                  \
        }                                                                      \
        f32x4 accv = accA + accB;                                              \
        float acc = (accv.x + accv.y) + (accv.z + accv.w);                     \
        acc += __shfl_xor(acc, 1, 64);                                         \
        acc += __shfl_xor(acc, 2, 64);                                         \
        if (sub == 0) { int o = gid; float sumv = acc; BODY }                  \
    }                                                                          \
    __syncthreads();

    // g1: 436 -> 256, tanh
    DENSE(436, 109, g1_w, in2, { aL[o] = ftanh(sumv + g1_b[o]); })
    // g2a: 256 -> 256, tanh
    DENSE(256, 64, g2a_w, aL, { bL[o] = ftanh(sumv + g2a_b[o]); })
    // g2b: + residual
    DENSE(256, 64, g2b_w, bL, { aL[o] = ftanh(sumv + g2b_b[o]) + aL[o]; })
    // g3a
    DENSE(256, 64, g3a_w, aL, { bL[o] = ftanh(sumv + g3a_b[o]); })
    // g3b: + residual
    DENSE(256, 64, g3b_w, bL, { aL[o] = ftanh(sumv + g3b_b[o]) + aL[o]; })
    // g4: 256 -> 180, + root_his_dct residual
    DENSE(256, 64, g4_w, aL, { if (o < 180) rp[o] = sumv + g4_b[o] + in2[o]; })

    // ---- IDCT: out[n,t,k] = sum_d idct_m[t,d] * rp[d*3+k] ----
    if (tid < 270) {
        int t = tid / 3;
        int k = tid - t * 3;
        const float* im = idct_m + t * 60;
        const float* rpp = rp + k;
        float acc = 0.f;
        #pragma unroll
        for (int d = 0; d < 60; ++d)
            acc += im[d] * rpp[d * 3];
        out[n * 270 + tid] = acc;
    }
}

// ---------------------------------------------------------------------------
extern "C" void kernel_launch(void* const* d_in, const int* in_sizes, int n_in,
                              void* d_out, int out_size, void* d_ws, size_t ws_size,
                              hipStream_t stream)
{
    const float* x        = (const float*)d_in[0];
    const float* cont     = (const float*)d_in[1];
    // d_in[2] cont_mask unused
    const float* dct_m    = (const float*)d_in[3];
    const float* idct_m   = (const float*)d_in[4];
    const int*   root_idx = (const int*)d_in[5];
    // d_in[6] horizon unused (hardcoded 60)
    const float* T_c      = (const float*)d_in[7];
    const float* A_c      = (const float*)d_in[8];
    const float* conv_w   = (const float*)d_in[9];
    const float* conv_b   = (const float*)d_in[10];
    const float* bn1_s    = (const float*)d_in[11];
    const float* bn1_sh   = (const float*)d_in[12];
    const float* rconv_w  = (const float*)d_in[13];
    const float* rconv_b  = (const float*)d_in[14];
    const float* bnr_s    = (const float*)d_in[15];
    const float* bnr_sh   = (const float*)d_in[16];
    const float* prelu_a  = (const float*)d_in[17];
    const float* te1_w    = (const float*)d_in[18];
    const float* te1_b    = (const float*)d_in[19];
    const float* te2_w    = (const float*)d_in[20];
    const float* te2_b    = (const float*)d_in[21];
    const float* ne1_w    = (const float*)d_in[22];
    const float* ne1_b    = (const float*)d_in[23];
    const float* ne2_w    = (const float*)d_in[24];
    const float* ne2_b    = (const float*)d_in[25];
    const float* g1_w     = (const float*)d_in[26];
    const float* g1_b     = (const float*)d_in[27];
    const float* g2a_w    = (const float*)d_in[28];
    const float* g2a_b    = (const float*)d_in[29];
    const float* g2b_w    = (const float*)d_in[30];
    const float* g2b_b    = (const float*)d_in[31];
    const float* g3a_w    = (const float*)d_in[32];
    const float* g3a_b    = (const float*)d_in[33];
    const float* g3b_w    = (const float*)d_in[34];
    const float* g3b_b    = (const float*)d_in[35];
    const float* g4_w     = (const float*)d_in[36];
    const float* g4_b     = (const float*)d_in[37];

    float* wsf = (float*)d_ws;   // NBS * WSROW floats

    k_p1<<<NBS, 1024, 0, stream>>>(x, cont, dct_m, root_idx,
                                   T_c, A_c,
                                   conv_w, conv_b, bn1_s, bn1_sh,
                                   rconv_w, rconv_b, bnr_s, bnr_sh,
                                   prelu_a,
                                   te1_w, te1_b, te2_w, te2_b,
                                   ne1_w, ne1_b, ne2_w, ne2_b,
                                   wsf);

    k_p2<<<NBS, 1024, 0, stream>>>(wsf,
                                   g1_w, g1_b, g2a_w, g2a_b, g2b_w, g2b_b,
                                   g3a_w, g3a_b, g3b_w, g3b_b, g4_w, g4_b,
                                   idct_m, (float*)d_out);
}

// Round 12
// 247.983 us; speedup vs baseline: 1.0092x; 1.0059x over previous
//
#include <hip/hip_runtime.h>

// Problem constants
#define NHID 256
#define NV   21
#define NT   60
#define NC   4
#define NDCT 60
#define THIS 30
#define NBS  256
#define WSROW 448   // floats per row in ws hand-off buffer (16B-aligned)

typedef float f32x2 __attribute__((ext_vector_type(2)));
typedef float f32x4 __attribute__((ext_vector_type(4)));

__device__ __forceinline__ float ftanh(float x) {
    // tanh(x) = 1 - 2/(exp(2x)+1); exact at +-inf, ~1e-6 rel error
    float e = __expf(2.0f * x);
    return 1.0f - __fdividef(2.0f, e + 1.0f);
}

// ---------------------------------------------------------------------------
// Kernel 1: STSGCN + conv/BN/PReLU + time/node encoders + root-DCT.
// One block per batch row, 1024 threads. Writes concat(root_dct, hcont)
// into ws[n*WSROW + 0..435].
// tew staged into LDS padded [60][12] (48B rows -> 16B aligned for all t):
// tw loads are b128+b128+b64 = 3 DS ops/iter instead of 5.
// ---------------------------------------------------------------------------
__global__ __launch_bounds__(1024, 4) void k_p1(
    const float* __restrict__ x,
    const float* __restrict__ cont,
    const float* __restrict__ dct_m,
    const int* __restrict__ root_idx,
    const float* __restrict__ T_c, const float* __restrict__ A_c,
    const float* __restrict__ conv_w, const float* __restrict__ conv_b,
    const float* __restrict__ bn1_scale, const float* __restrict__ bn1_shift,
    const float* __restrict__ resconv_w, const float* __restrict__ resconv_b,
    const float* __restrict__ bnr_scale, const float* __restrict__ bnr_shift,
    const float* __restrict__ prelu_a_p,
    const float* __restrict__ te1_w, const float* __restrict__ te1_b,
    const float* __restrict__ te2_w, const float* __restrict__ te2_b,
    const float* __restrict__ ne1_w, const float* __restrict__ ne1_b,
    const float* __restrict__ ne2_w, const float* __restrict__ ne2_b,
    float* __restrict__ ws)
{
    __shared__ __align__(16) float xc_lds[5040];   // [t][v][c]
    __shared__ __align__(16) float g_lds[5040];    // [q][v][c]; then tew[60][12]
    __shared__ __align__(16) float g2_lds[5040];   // [t][w][c]

    const int n   = blockIdx.x;
    const int tid = threadIdx.x;

    // ---- stage A: cont[n] -> LDS (layout already [t][v][c]) ----
    {
        const float4* src = (const float4*)(cont + n * 5040);
        float4* dst = (float4*)xc_lds;
        for (int i = tid; i < 1260; i += 1024) dst[i] = src[i];
    }
    __syncthreads();

    // ---- stage B: g[q][v][c] = sum_t xc[t][v][c] * T_c[v][t][q], q-pairs ----
    for (int task = tid; task < 630; task += 1024) {
        int v  = task / 30;           // 0..20
        int q0 = (task - v * 30) * 2; // 0,2,..,58
        const float* tc = T_c + v * 3600 + q0;   // + t*60
        f32x4 a0 = {0.f,0.f,0.f,0.f}, a1 = {0.f,0.f,0.f,0.f};
        #pragma unroll 4
        for (int t = 0; t < 60; ++t) {
            f32x4 xcv = *(const f32x4*)(xc_lds + t * 84 + v * 4);
            float2 tq = *(const float2*)(tc + t * 60);   // 8B-aligned (q0 even)
            a0 += xcv * tq.x;
            a1 += xcv * tq.y;
        }
        *(f32x4*)(g_lds + q0 * 84 + v * 4)       = a0;
        *(f32x4*)(g_lds + (q0 + 1) * 84 + v * 4) = a1;
    }
    __syncthreads();

    // ---- stage C: g2[t][w][c] = sum_v g[t][v][c] * A_c[t][v][w], w-pairs ----
    for (int task = tid; task < 660; task += 1024) {
        int t  = task / 11;            // 0..59
        int w0 = (task - t * 11) * 2;  // 0,2,..,20 (w0==20 -> single)
        const bool has2 = (w0 < 20);
        const float* ac = A_c + t * 441 + w0;   // + v*21
        f32x4 a0 = {0.f,0.f,0.f,0.f}, a1 = {0.f,0.f,0.f,0.f};
        #pragma unroll
        for (int v = 0; v < 21; ++v) {
            f32x4 gv = *(const f32x4*)(g_lds + t * 84 + v * 4);
            float b0 = ac[v * 21];
            float b1 = has2 ? ac[v * 21 + 1] : 0.f;
            a0 += gv * b0;
            a1 += gv * b1;
        }
        *(f32x4*)(g2_lds + t * 84 + w0 * 4) = a0;
        if (has2) *(f32x4*)(g2_lds + t * 84 + (w0 + 1) * 4) = a1;
    }
    __syncthreads();
    // g_lds dead as adjacency scratch.

    float* tew = g_lds;   // [60][12] padded: te1_w transposed

    // ---- stage tew (te1_w [10][60] -> tew[t][j], pad j=10,11) + root-DCT ----
    if (tid < 720) {
        int t = tid / 12, j = tid - t * 12;
        tew[tid] = (j < 10) ? te1_w[j * 60 + t] : 0.f;
    } else if (tid >= 720 && tid < 900) {
        int r = tid - 720;
        int d = r / 3, k = r - d * 3;
        int ri = root_idx[k];
        const float* xp = x + n * 63 + ri;   // + t*16128
        const float* dm = dct_m + d * 90;
        float acc = 0.f;
        #pragma unroll
        for (int t = 0; t < 30; ++t)
            acc += dm[t] * xp[t * 16128];
        float wl = 0.f;
        #pragma unroll
        for (int t = 30; t < 90; ++t)
            wl += dm[t];
        acc += wl * xp[29 * 16128];
        ws[n * WSROW + r] = acc;
    }
    __syncthreads();

    // ---- main fused loop: 2 o-channels per thread ----
    {
        const int og = tid >> 3;     // 0..127 -> o = og*2+g
        const int part = tid & 7;    // 0..7   -> v slice
        const int vstart = (part < 5) ? part * 3 : 15 + (part - 5) * 2;
        const int vcount = (part < 5) ? 3 : 2;

        const float pa = prelu_a_p[0];

        f32x2 cA01[2], cA23[2], cB01[2], cB23[2];
        float cC[2];
        #pragma unroll
        for (int g = 0; g < 2; ++g) {
            int o = og * 2 + g;
            float s1 = bn1_scale[o], sr = bnr_scale[o];
            cA01[g] = (f32x2){conv_w[o*4+0] * s1, conv_w[o*4+1] * s1};
            cA23[g] = (f32x2){conv_w[o*4+2] * s1, conv_w[o*4+3] * s1};
            cB01[g] = (f32x2){resconv_w[o*4+0] * sr, resconv_w[o*4+1] * sr};
            cB23[g] = (f32x2){resconv_w[o*4+2] * sr, resconv_w[o*4+3] * sr};
            cC[g] = conv_b[o] * s1 + bn1_shift[o] + resconv_b[o] * sr + bnr_shift[o];
        }

        float tw2[10], tb1[10];
        #pragma unroll
        for (int j = 0; j < 10; ++j) { tw2[j] = te2_w[j]; tb1[j] = te1_b[j]; }
        const float tb2 = te2_b[0];

        float wacc[2][10];
        #pragma unroll
        for (int g = 0; g < 2; ++g)
            #pragma unroll
            for (int j = 0; j < 10; ++j) wacc[g][j] = 0.f;

        for (int vi = 0; vi < vcount; ++vi) {
            int v = vstart + vi;
            f32x2 u2[2][5];
            #pragma unroll
            for (int g = 0; g < 2; ++g)
                #pragma unroll
                for (int p = 0; p < 5; ++p)
                    u2[g][p] = (f32x2){tb1[2*p], tb1[2*p+1]};

            const float* xcp = xc_lds + v * 4;
            const float* g2p = g2_lds + v * 4;
            for (int t = 0; t < 60; ++t) {
                f32x4 xcv = *(const f32x4*)(xcp + t * 84);
                f32x4 g2v = *(const f32x4*)(g2p + t * 84);
                // tw: 3 uniform DS broadcasts (b128+b128+b64), 16B-aligned rows
                const float* twp = tew + t * 12;
                f32x4 t03 = *(const f32x4*)(twp);
                f32x4 t47 = *(const f32x4*)(twp + 4);
                f32x2 t89 = *(const f32x2*)(twp + 8);
                f32x2 tw[5] = { {t03.x,t03.y}, {t03.z,t03.w},
                                {t47.x,t47.y}, {t47.z,t47.w}, t89 };
                f32x2 g01 = {g2v.x, g2v.y}, g23 = {g2v.z, g2v.w};
                f32x2 x01 = {xcv.x, xcv.y}, x23 = {xcv.z, xcv.w};
                #pragma unroll
                for (int g = 0; g < 2; ++g) {
                    f32x2 hv = {cC[g], 0.f};
                    hv += cA01[g] * g01;
                    hv += cA23[g] * g23;
                    hv += cB01[g] * x01;
                    hv += cB23[g] * x23;
                    float h = hv.x + hv.y;
                    h = fmaxf(h, 0.f) + pa * fminf(h, 0.f);   // PReLU (3 ops w/ fma)
                    #pragma unroll
                    for (int p = 0; p < 5; ++p)
                        u2[g][p] += h * tw[p];
                }
            }

            float nw[10];
            #pragma unroll
            for (int j = 0; j < 10; ++j) nw[j] = ne1_w[j * 21 + v];
            #pragma unroll
            for (int g = 0; g < 2; ++g) {
                float s = tb2;
                #pragma unroll
                for (int p = 0; p < 5; ++p) {
                    s += ftanh(u2[g][p].x) * tw2[2*p];
                    s += ftanh(u2[g][p].y) * tw2[2*p+1];
                }
                s = ftanh(s);
                #pragma unroll
                for (int j = 0; j < 10; ++j) wacc[g][j] += s * nw[j];
            }
        }

        // butterfly reduce over the 8 v-parts (tid low 3 bits)
        #pragma unroll
        for (int d = 1; d < 8; d <<= 1)
            #pragma unroll
            for (int g = 0; g < 2; ++g)
                #pragma unroll
                for (int j = 0; j < 10; ++j)
                    wacc[g][j] += __shfl_xor(wacc[g][j], d, 64);

        if (part == 0) {
            float nw2[10];
            #pragma unroll
            for (int j = 0; j < 10; ++j) nw2[j] = ne2_w[j];
            float nb2 = ne2_b[0];
            #pragma unroll
            for (int g = 0; g < 2; ++g) {
                int o = og * 2 + g;
                float s = nb2;
                #pragma unroll
                for (int j = 0; j < 10; ++j)
                    s += ftanh(wacc[g][j] + ne1_b[j]) * nw2[j];
                ws[n * WSROW + 180 + o] = ftanh(s);
            }
        }
    }
}

// ---------------------------------------------------------------------------
// Kernel 2: residual MLP head + IDCT. One block per batch row, 1024 threads.
// 4-lane k-split per output (2 shfl rounds). Reads ws[n*WSROW + 0..435].
// ---------------------------------------------------------------------------
__global__ __launch_bounds__(1024, 4) void k_p2(
    const float* __restrict__ ws,
    const float* __restrict__ g1_w, const float* __restrict__ g1_b,
    const float* __restrict__ g2a_w, const float* __restrict__ g2a_b,
    const float* __restrict__ g2b_w, const float* __restrict__ g2b_b,
    const float* __restrict__ g3a_w, const float* __restrict__ g3a_b,
    const float* __restrict__ g3b_w, const float* __restrict__ g3b_b,
    const float* __restrict__ g4_w, const float* __restrict__ g4_b,
    const float* __restrict__ idct_m, float* __restrict__ out)
{
    __shared__ __align__(16) float in2[436];
    __shared__ __align__(16) float aL[256];
    __shared__ __align__(16) float bL[256];
    __shared__ __align__(16) float rp[180];

    const int n   = blockIdx.x;
    const int tid = threadIdx.x;

    // stage in2 from ws
    if (tid < 109) {
        *(f32x4*)(in2 + tid * 4) = *(const f32x4*)(ws + n * WSROW + tid * 4);
    }
    __syncthreads();

    const int gid = tid >> 2;    // 0..255 = output index o
    const int sub = tid & 3;     // 0..3   = k-slice lane

// K inputs (NCHUNK float4 chunks), 256 outputs. BODY uses (o, sumv).
#define DENSE(KDIM, NCHUNK, W, SRC, BODY)                                      \
    {                                                                          \
        f32x4 accA = {0.f,0.f,0.f,0.f}, accB = {0.f,0.f,0.f,0.f};              \
        _Pragma("unroll")                                                      \
        for (int s = 0; s < (NCHUNK + 7) / 8; ++s) {                           \
            int c4 = s * 8 + sub;                                              \
            if (c4 < NCHUNK) {                                                 \
                f32x4 av = *(const f32x4*)&SRC[c4 * 4];                        \
                f32x4 wv = *(const f32x4*)&W[gid * KDIM + c4 * 4];             \
                accA += av * wv;                                               \
            }                                                                  \
            int c4b = s * 8 + 4 + sub;                                         \
            if (c4b < NCHUNK) {                                                \
                f32x4 av = *(const f32x4*)&SRC[c4b * 4];                       \
                f32x4 wv = *(const f32x4*)&W[gid * KDIM + c4b * 4];            \
                accB += av * wv;                                               \
            }                                                                  \
        }                                                                      \
        f32x4 accv = accA + accB;                                              \
        float acc = (accv.x + accv.y) + (accv.z + accv.w);                     \
        acc += __shfl_xor(acc, 1, 64);                                         \
        acc += __shfl_xor(acc, 2, 64);                                         \
        if (sub == 0) { int o = gid; float sumv = acc; BODY }                  \
    }                                                                          \
    __syncthreads();

    // g1: 436 -> 256, tanh
    DENSE(436, 109, g1_w, in2, { aL[o] = ftanh(sumv + g1_b[o]); })
    // g2a: 256 -> 256, tanh
    DENSE(256, 64, g2a_w, aL, { bL[o] = ftanh(sumv + g2a_b[o]); })
    // g2b: + residual
    DENSE(256, 64, g2b_w, bL, { aL[o] = ftanh(sumv + g2b_b[o]) + aL[o]; })
    // g3a
    DENSE(256, 64, g3a_w, aL, { bL[o] = ftanh(sumv + g3a_b[o]); })
    // g3b: + residual
    DENSE(256, 64, g3b_w, bL, { aL[o] = ftanh(sumv + g3b_b[o]) + aL[o]; })
    // g4: 256 -> 180, + root_his_dct residual
    DENSE(256, 64, g4_w, aL, { if (o < 180) rp[o] = sumv + g4_b[o] + in2[o]; })

    // ---- IDCT: out[n,t,k] = sum_d idct_m[t,d] * rp[d*3+k] ----
    if (tid < 270) {
        int t = tid / 3;
        int k = tid - t * 3;
        const float* im = idct_m + t * 60;
        const float* rpp = rp + k;
        float acc = 0.f;
        #pragma unroll
        for (int d = 0; d < 60; ++d)
            acc += im[d] * rpp[d * 3];
        out[n * 270 + tid] = acc;
    }
}

// ---------------------------------------------------------------------------
extern "C" void kernel_launch(void* const* d_in, const int* in_sizes, int n_in,
                              void* d_out, int out_size, void* d_ws, size_t ws_size,
                              hipStream_t stream)
{
    const float* x        = (const float*)d_in[0];
    const float* cont     = (const float*)d_in[1];
    // d_in[2] cont_mask unused
    const float* dct_m    = (const float*)d_in[3];
    const float* idct_m   = (const float*)d_in[4];
    const int*   root_idx = (const int*)d_in[5];
    // d_in[6] horizon unused (hardcoded 60)
    const float* T_c      = (const float*)d_in[7];
    const float* A_c      = (const float*)d_in[8];
    const float* conv_w   = (const float*)d_in[9];
    const float* conv_b   = (const float*)d_in[10];
    const float* bn1_s    = (const float*)d_in[11];
    const float* bn1_sh   = (const float*)d_in[12];
    const float* rconv_w  = (const float*)d_in[13];
    const float* rconv_b  = (const float*)d_in[14];
    const float* bnr_s    = (const float*)d_in[15];
    const float* bnr_sh   = (const float*)d_in[16];
    const float* prelu_a  = (const float*)d_in[17];
    const float* te1_w    = (const float*)d_in[18];
    const float* te1_b    = (const float*)d_in[19];
    const float* te2_w    = (const float*)d_in[20];
    const float* te2_b    = (const float*)d_in[21];
    const float* ne1_w    = (const float*)d_in[22];
    const float* ne1_b    = (const float*)d_in[23];
    const float* ne2_w    = (const float*)d_in[24];
    const float* ne2_b    = (const float*)d_in[25];
    const float* g1_w     = (const float*)d_in[26];
    const float* g1_b     = (const float*)d_in[27];
    const float* g2a_w    = (const float*)d_in[28];
    const float* g2a_b    = (const float*)d_in[29];
    const float* g2b_w    = (const float*)d_in[30];
    const float* g2b_b    = (const float*)d_in[31];
    const float* g3a_w    = (const float*)d_in[32];
    const float* g3a_b    = (const float*)d_in[33];
    const float* g3b_w    = (const float*)d_in[34];
    const float* g3b_b    = (const float*)d_in[35];
    const float* g4_w     = (const float*)d_in[36];
    const float* g4_b     = (const float*)d_in[37];

    float* wsf = (float*)d_ws;   // NBS * WSROW floats

    k_p1<<<NBS, 1024, 0, stream>>>(x, cont, dct_m, root_idx,
                                   T_c, A_c,
                                   conv_w, conv_b, bn1_s, bn1_sh,
                                   rconv_w, rconv_b, bnr_s, bnr_sh,
                                   prelu_a,
                                   te1_w, te1_b, te2_w, te2_b,
                                   ne1_w, ne1_b, ne2_w, ne2_b,
                                   wsf);

    k_p2<<<NBS, 1024, 0, stream>>>(wsf,
                                   g1_w, g1_b, g2a_w, g2a_b, g2b_w, g2b_b,
                                   g3a_w, g3a_b, g3b_w, g3b_b, g4_w, g4_b,
                                   idct_m, (float*)d_out);
}

// Round 14
// 239.584 us; speedup vs baseline: 1.0445x; 1.0351x over previous
//
#include <hip/hip_runtime.h>

// Problem constants
#define NHID 256
#define NV   21
#define NT   60
#define NC   4
#define NDCT 60
#define THIS 30
#define NBS  256
#define WSROW 448   // floats per row in ws hand-off buffer (16B-aligned)

typedef float f32x2 __attribute__((ext_vector_type(2)));
typedef float f32x4 __attribute__((ext_vector_type(4)));

__device__ __forceinline__ float ftanh(float x) {
    // tanh(x) = 1 - 2/(exp(2x)+1); exact at +-inf, ~1e-6 rel error
    float e = __expf(2.0f * x);
    return 1.0f - __fdividef(2.0f, e + 1.0f);
}

// ---------------------------------------------------------------------------
// Kernel 1: STSGCN + conv/BN/PReLU + time/node encoders + root-DCT.
// 512 threads (8 waves/CU), G=4 o-channels per thread: halves per-CU LDS
// read traffic in the main loop (DS pipe is the measured bound, ~byte-limited).
// ---------------------------------------------------------------------------
__global__ __launch_bounds__(512, 2) void k_p1(
    const float* __restrict__ x,
    const float* __restrict__ cont,
    const float* __restrict__ dct_m,
    const int* __restrict__ root_idx,
    const float* __restrict__ T_c, const float* __restrict__ A_c,
    const float* __restrict__ conv_w, const float* __restrict__ conv_b,
    const float* __restrict__ bn1_scale, const float* __restrict__ bn1_shift,
    const float* __restrict__ resconv_w, const float* __restrict__ resconv_b,
    const float* __restrict__ bnr_scale, const float* __restrict__ bnr_shift,
    const float* __restrict__ prelu_a_p,
    const float* __restrict__ te1_w, const float* __restrict__ te1_b,
    const float* __restrict__ te2_w, const float* __restrict__ te2_b,
    const float* __restrict__ ne1_w, const float* __restrict__ ne1_b,
    const float* __restrict__ ne2_w, const float* __restrict__ ne2_b,
    float* __restrict__ ws)
{
    __shared__ __align__(16) float xc_lds[5040];   // [t][v][c]
    __shared__ __align__(16) float g_lds[5040];    // [q][v][c]; then tew[60][12]
    __shared__ __align__(16) float g2_lds[5040];   // [t][w][c]

    const int n   = blockIdx.x;
    const int tid = threadIdx.x;

    // ---- stage A: cont[n] -> LDS (layout already [t][v][c]) ----
    {
        const float4* src = (const float4*)(cont + n * 5040);
        float4* dst = (float4*)xc_lds;
        for (int i = tid; i < 1260; i += 512) dst[i] = src[i];
    }
    __syncthreads();

    // ---- stage B: g[q][v][c] = sum_t xc[t][v][c] * T_c[v][t][q], q-pairs ----
    for (int task = tid; task < 630; task += 512) {
        int v  = task / 30;           // 0..20
        int q0 = (task - v * 30) * 2; // 0,2,..,58
        const float* tc = T_c + v * 3600 + q0;   // + t*60
        f32x4 a0 = {0.f,0.f,0.f,0.f}, a1 = {0.f,0.f,0.f,0.f};
        #pragma unroll 4
        for (int t = 0; t < 60; ++t) {
            f32x4 xcv = *(const f32x4*)(xc_lds + t * 84 + v * 4);
            float2 tq = *(const float2*)(tc + t * 60);   // 8B-aligned (q0 even)
            a0 += xcv * tq.x;
            a1 += xcv * tq.y;
        }
        *(f32x4*)(g_lds + q0 * 84 + v * 4)       = a0;
        *(f32x4*)(g_lds + (q0 + 1) * 84 + v * 4) = a1;
    }
    __syncthreads();

    // ---- stage C: g2[t][w][c] = sum_v g[t][v][c] * A_c[t][v][w], w-pairs ----
    for (int task = tid; task < 660; task += 512) {
        int t  = task / 11;            // 0..59
        int w0 = (task - t * 11) * 2;  // 0,2,..,20 (w0==20 -> single)
        const bool has2 = (w0 < 20);
        const float* ac = A_c + t * 441 + w0;   // + v*21
        f32x4 a0 = {0.f,0.f,0.f,0.f}, a1 = {0.f,0.f,0.f,0.f};
        #pragma unroll
        for (int v = 0; v < 21; ++v) {
            f32x4 gv = *(const f32x4*)(g_lds + t * 84 + v * 4);
            float b0 = ac[v * 21];
            float b1 = has2 ? ac[v * 21 + 1] : 0.f;
            a0 += gv * b0;
            a1 += gv * b1;
        }
        *(f32x4*)(g2_lds + t * 84 + w0 * 4) = a0;
        if (has2) *(f32x4*)(g2_lds + t * 84 + (w0 + 1) * 4) = a1;
    }
    __syncthreads();
    // g_lds dead as adjacency scratch.

    float* tew = g_lds;   // [60][12] padded: te1_w transposed

    // ---- stage tew (te1_w [10][60] -> tew[t][j], pad j=10,11) ----
    for (int i = tid; i < 720; i += 512) {
        int t = i / 12, j = i - t * 12;
        tew[i] = (j < 10) ? te1_w[j * 60 + t] : 0.f;
    }
    // ---- root-history DCT -> ws[n*WSROW + 0..179] ----
    if (tid < 180) {
        int d = tid / 3, k = tid - d * 3;
        int ri = root_idx[k];
        const float* xp = x + n * 63 + ri;   // + t*16128
        const float* dm = dct_m + d * 90;
        float acc = 0.f;
        #pragma unroll
        for (int t = 0; t < 30; ++t)
            acc += dm[t] * xp[t * 16128];
        float wl = 0.f;
        #pragma unroll
        for (int t = 30; t < 90; ++t)
            wl += dm[t];
        acc += wl * xp[29 * 16128];
        ws[n * WSROW + tid] = acc;
    }
    __syncthreads();

    // ---- main fused loop: 4 o-channels per thread ----
    {
        const int og = tid >> 3;     // 0..63 -> o = og*4+g
        const int part = tid & 7;    // 0..7  -> v slice
        const int vstart = (part < 5) ? part * 3 : 15 + (part - 5) * 2;
        const int vcount = (part < 5) ? 3 : 2;
        const int obase = og * 4;

        const float pa = prelu_a_p[0];

        f32x2 cA01[4], cA23[4], cB01[4], cB23[4];
        float cC[4];
        #pragma unroll
        for (int g = 0; g < 4; ++g) {
            int o = obase + g;
            float s1 = bn1_scale[o], sr = bnr_scale[o];
            cA01[g] = (f32x2){conv_w[o*4+0] * s1, conv_w[o*4+1] * s1};
            cA23[g] = (f32x2){conv_w[o*4+2] * s1, conv_w[o*4+3] * s1};
            cB01[g] = (f32x2){resconv_w[o*4+0] * sr, resconv_w[o*4+1] * sr};
            cB23[g] = (f32x2){resconv_w[o*4+2] * sr, resconv_w[o*4+3] * sr};
            cC[g] = conv_b[o] * s1 + bn1_shift[o] + resconv_b[o] * sr + bnr_shift[o];
        }

        float tw2[10], tb1[10];
        #pragma unroll
        for (int j = 0; j < 10; ++j) { tw2[j] = te2_w[j]; tb1[j] = te1_b[j]; }
        const float tb2 = te2_b[0];

        float wacc[4][10];
        #pragma unroll
        for (int g = 0; g < 4; ++g)
            #pragma unroll
            for (int j = 0; j < 10; ++j) wacc[g][j] = 0.f;

        for (int vi = 0; vi < vcount; ++vi) {
            int v = vstart + vi;
            f32x2 u2[4][5];
            #pragma unroll
            for (int g = 0; g < 4; ++g)
                #pragma unroll
                for (int p = 0; p < 5; ++p)
                    u2[g][p] = (f32x2){tb1[2*p], tb1[2*p+1]};

            const float* xcp = xc_lds + v * 4;
            const float* g2p = g2_lds + v * 4;
            for (int t = 0; t < 60; ++t) {
                f32x4 xcv = *(const f32x4*)(xcp + t * 84);
                f32x4 g2v = *(const f32x4*)(g2p + t * 84);
                const float* twp = tew + t * 12;
                f32x4 t03 = *(const f32x4*)(twp);
                f32x4 t47 = *(const f32x4*)(twp + 4);
                f32x2 t89 = *(const f32x2*)(twp + 8);
                f32x2 tw[5] = { {t03.x,t03.y}, {t03.z,t03.w},
                                {t47.x,t47.y}, {t47.z,t47.w}, t89 };
                f32x2 g01 = {g2v.x, g2v.y}, g23 = {g2v.z, g2v.w};
                f32x2 x01 = {xcv.x, xcv.y}, x23 = {xcv.z, xcv.w};
                #pragma unroll
                for (int g = 0; g < 4; ++g) {
                    f32x2 hv = {cC[g], 0.f};
                    hv += cA01[g] * g01;
                    hv += cA23[g] * g23;
                    hv += cB01[g] * x01;
                    hv += cB23[g] * x23;
                    float h = hv.x + hv.y;
                    h = fmaxf(h, 0.f) + pa * fminf(h, 0.f);   // PReLU
                    #pragma unroll
                    for (int p = 0; p < 5; ++p)
                        u2[g][p] += h * tw[p];
                }
            }

            float nw[10];
            #pragma unroll
            for (int j = 0; j < 10; ++j) nw[j] = ne1_w[j * 21 + v];
            #pragma unroll
            for (int g = 0; g < 4; ++g) {
                float s = tb2;
                #pragma unroll
                for (int p = 0; p < 5; ++p) {
                    s += ftanh(u2[g][p].x) * tw2[2*p];
                    s += ftanh(u2[g][p].y) * tw2[2*p+1];
                }
                s = ftanh(s);
                #pragma unroll
                for (int j = 0; j < 10; ++j) wacc[g][j] += s * nw[j];
            }
        }

        // butterfly reduce over the 8 v-parts (tid low 3 bits)
        #pragma unroll
        for (int d = 1; d < 8; d <<= 1)
            #pragma unroll
            for (int g = 0; g < 4; ++g)
                #pragma unroll
                for (int j = 0; j < 10; ++j)
                    wacc[g][j] += __shfl_xor(wacc[g][j], d, 64);

        if (part == 0) {
            float nw2[10];
            #pragma unroll
            for (int j = 0; j < 10; ++j) nw2[j] = ne2_w[j];
            float nb2 = ne2_b[0];
            #pragma unroll
            for (int g = 0; g < 4; ++g) {
                int o = obase + g;
                float s = nb2;
                #pragma unroll
                for (int j = 0; j < 10; ++j)
                    s += ftanh(wacc[g][j] + ne1_b[j]) * nw2[j];
                ws[n * WSROW + 180 + o] = ftanh(s);
            }
        }
    }
}

// ---------------------------------------------------------------------------
// Kernel 2: residual MLP head + IDCT. TWO batch rows per block (grid 128):
// each weight float4 feeds 2 row-accumulators -> L2 weight traffic halved.
// 1024 threads, 4-lane k-split per output.
// ---------------------------------------------------------------------------
__global__ __launch_bounds__(1024, 4) void k_p2(
    const float* __restrict__ ws,
    const float* __restrict__ g1_w, const float* __restrict__ g1_b,
    const float* __restrict__ g2a_w, const float* __restrict__ g2a_b,
    const float* __restrict__ g2b_w, const float* __restrict__ g2b_b,
    const float* __restrict__ g3a_w, const float* __restrict__ g3a_b,
    const float* __restrict__ g3b_w, const float* __restrict__ g3b_b,
    const float* __restrict__ g4_w, const float* __restrict__ g4_b,
    const float* __restrict__ idct_m, float* __restrict__ out)
{
    __shared__ __align__(16) float in2[2][436];
    __shared__ __align__(16) float aL[2][256];
    __shared__ __align__(16) float bL[2][256];
    __shared__ __align__(16) float rp[2][180];

    const int n0  = blockIdx.x * 2;
    const int tid = threadIdx.x;

    // stage in2 from ws (both rows)
    if (tid < 218) {
        int bn = tid / 109, i = tid - bn * 109;
        *(f32x4*)(&in2[bn][i * 4]) = *(const f32x4*)(ws + (n0 + bn) * WSROW + i * 4);
    }
    __syncthreads();

    const int gid = tid >> 2;    // 0..255 = output index o
    const int sub = tid & 3;     // 0..3   = k-slice lane

// K inputs (NCHUNK float4 chunks), 256 outputs, 2 rows sharing weight loads.
#define DENSE(KDIM, NCHUNK, W, S0, S1, BODY)                                   \
    {                                                                          \
        f32x4 acc0 = {0.f,0.f,0.f,0.f}, acc1 = {0.f,0.f,0.f,0.f};              \
        _Pragma("unroll")                                                      \
        for (int s = 0; s < (NCHUNK + 3) / 4; ++s) {                           \
            int c4 = s * 4 + sub;                                              \
            if (c4 < NCHUNK) {                                                 \
                f32x4 wv = *(const f32x4*)&W[gid * KDIM + c4 * 4];             \
                f32x4 a0 = *(const f32x4*)&S0[c4 * 4];                         \
                f32x4 a1 = *(const f32x4*)&S1[c4 * 4];                         \
                acc0 += a0 * wv;                                               \
                acc1 += a1 * wv;                                               \
            }                                                                  \
        }                                                                      \
        float r0 = (acc0.x + acc0.y) + (acc0.z + acc0.w);                      \
        float r1 = (acc1.x + acc1.y) + (acc1.z + acc1.w);                      \
        r0 += __shfl_xor(r0, 1, 64);  r1 += __shfl_xor(r1, 1, 64);             \
        r0 += __shfl_xor(r0, 2, 64);  r1 += __shfl_xor(r1, 2, 64);             \
        if (sub == 0) { int o = gid; BODY }                                    \
    }                                                                          \
    __syncthreads();

    // g1: 436 -> 256, tanh
    DENSE(436, 109, g1_w, in2[0], in2[1],
        { aL[0][o] = ftanh(r0 + g1_b[o]); aL[1][o] = ftanh(r1 + g1_b[o]); })
    // g2a: 256 -> 256, tanh
    DENSE(256, 64, g2a_w, aL[0], aL[1],
        { bL[0][o] = ftanh(r0 + g2a_b[o]); bL[1][o] = ftanh(r1 + g2a_b[o]); })
    // g2b: + residual
    DENSE(256, 64, g2b_w, bL[0], bL[1],
        { aL[0][o] = ftanh(r0 + g2b_b[o]) + aL[0][o];
          aL[1][o] = ftanh(r1 + g2b_b[o]) + aL[1][o]; })
    // g3a
    DENSE(256, 64, g3a_w, aL[0], aL[1],
        { bL[0][o] = ftanh(r0 + g3a_b[o]); bL[1][o] = ftanh(r1 + g3a_b[o]); })
    // g3b: + residual
    DENSE(256, 64, g3b_w, bL[0], bL[1],
        { aL[0][o] = ftanh(r0 + g3b_b[o]) + aL[0][o];
          aL[1][o] = ftanh(r1 + g3b_b[o]) + aL[1][o]; })
    // g4: 256 -> 180, + root_his_dct residual
    DENSE(256, 64, g4_w, aL[0], aL[1],
        { if (o < 180) { rp[0][o] = r0 + g4_b[o] + in2[0][o];
                         rp[1][o] = r1 + g4_b[o] + in2[1][o]; } })

    // ---- IDCT: out[n,t,k] = sum_d idct_m[t,d] * rp[d*3+k] ----
    for (int idx = tid; idx < 2 * 270; idx += 1024) {
        int bn = idx / 270;
        int r = idx - bn * 270;
        int t = r / 3;
        int k = r - t * 3;
        const float* im = idct_m + t * 60;
        const float* rpp = &rp[bn][k];
        float acc = 0.f;
        #pragma unroll
        for (int d = 0; d < 60; ++d)
            acc += im[d] * rpp[d * 3];
        out[(n0 + bn) * 270 + r] = acc;
    }
}

// ---------------------------------------------------------------------------
extern "C" void kernel_launch(void* const* d_in, const int* in_sizes, int n_in,
                              void* d_out, int out_size, void* d_ws, size_t ws_size,
                              hipStream_t stream)
{
    const float* x        = (const float*)d_in[0];
    const float* cont     = (const float*)d_in[1];
    // d_in[2] cont_mask unused
    const float* dct_m    = (const float*)d_in[3];
    const float* idct_m   = (const float*)d_in[4];
    const int*   root_idx = (const int*)d_in[5];
    // d_in[6] horizon unused (hardcoded 60)
    const float* T_c      = (const float*)d_in[7];
    const float* A_c      = (const float*)d_in[8];
    const float* conv_w   = (const float*)d_in[9];
    const float* conv_b   = (const float*)d_in[10];
    const float* bn1_s    = (const float*)d_in[11];
    const float* bn1_sh   = (const float*)d_in[12];
    const float* rconv_w  = (const float*)d_in[13];
    const float* rconv_b  = (const float*)d_in[14];
    const float* bnr_s    = (const float*)d_in[15];
    const float* bnr_sh   = (const float*)d_in[16];
    const float* prelu_a  = (const float*)d_in[17];
    const float* te1_w    = (const float*)d_in[18];
    const float* te1_b    = (const float*)d_in[19];
    const float* te2_w    = (const float*)d_in[20];
    const float* te2_b    = (const float*)d_in[21];
    const float* ne1_w    = (const float*)d_in[22];
    const float* ne1_b    = (const float*)d_in[23];
    const float* ne2_w    = (const float*)d_in[24];
    const float* ne2_b    = (const float*)d_in[25];
    const float* g1_w     = (const float*)d_in[26];
    const float* g1_b     = (const float*)d_in[27];
    const float* g2a_w    = (const float*)d_in[28];
    const float* g2a_b    = (const float*)d_in[29];
    const float* g2b_w    = (const float*)d_in[30];
    const float* g2b_b    = (const float*)d_in[31];
    const float* g3a_w    = (const float*)d_in[32];
    const float* g3a_b    = (const float*)d_in[33];
    const float* g3b_w    = (const float*)d_in[34];
    const float* g3b_b    = (const float*)d_in[35];
    const float* g4_w     = (const float*)d_in[36];
    const float* g4_b     = (const float*)d_in[37];

    float* wsf = (float*)d_ws;   // NBS * WSROW floats

    k_p1<<<NBS, 512, 0, stream>>>(x, cont, dct_m, root_idx,
                                  T_c, A_c,
                                  conv_w, conv_b, bn1_s, bn1_sh,
                                  rconv_w, rconv_b, bnr_s, bnr_sh,
                                  prelu_a,
                                  te1_w, te1_b, te2_w, te2_b,
                                  ne1_w, ne1_b, ne2_w, ne2_b,
                                  wsf);

    k_p2<<<NBS / 2, 1024, 0, stream>>>(wsf,
                                       g1_w, g1_b, g2a_w, g2a_b, g2b_w, g2b_b,
                                       g3a_w, g3a_b, g3b_w, g3b_b, g4_w, g4_b,
                                       idct_m, (float*)d_out);
}